// Round 10
// baseline (618.570 us; speedup 1.0000x reference)
//
#include <hip/hip_runtime.h>
#include <hip/hip_bf16.h>

#define NS 8
#define NF 210
#define HID 128

typedef __attribute__((ext_vector_type(8))) short short8v;     // 8 bf16 = 4 VGPR MFMA A/B frag
typedef __attribute__((ext_vector_type(4))) float float4v;     // MFMA C/D frag
typedef float float4a __attribute__((ext_vector_type(4)));                 // 16B-aligned load
typedef float float4u __attribute__((ext_vector_type(4), aligned(4)));     // 4B-aligned global read
typedef float float2u __attribute__((ext_vector_type(2), aligned(8)));

__device__ __forceinline__ short f2b(float f) {
    __hip_bfloat16 h = __float2bfloat16(f);   // RNE; pairs fuse to v_cvt_pk_bf16_f32
    return __builtin_bit_cast(short, h);
}

#define MFMA16(a, b, cacc) __builtin_amdgcn_mfma_f32_16x16x32_bf16(a, b, cacc, 0, 0, 0)

// ---------------------------------------------------------------------------
// pre_kernel: blocks [0,304) = weight repack; blocks [304,816) = station path.
// Weight repack (W^T A-frags, lane-linear per (nc,kc) -> conflict-free
// ds_read_b128):
//   W1 : [0,28672)         idx = (((nc*7+kc)*4+kg)*16 + c)*8 + j
//   WsL: 28672+l*16384 +   idx = (((nc*4+kc)*4+kg)*16 + c)*8 + j
//   frag elem j of lane (c,kg): n = 16nc+c, k = kc*32+16(j>>2)+4kg+(j&3)
// Station path emits c_all[g][l][:] = mean_l[g] @ Wneigh_hf[l] + b_hf[l] and
// d_out[g] = rs[g]*W_out[0] + b_out (feature kernel atomic-adds rf part).
// ---------------------------------------------------------------------------
__global__ __launch_bounds__(256) void pre_kernel(
    const float* __restrict__ W1_ft, const float* __restrict__ Wself_hf,
    unsigned short* __restrict__ wsb,
    const float* __restrict__ h_st, const float* __restrict__ W1_st, const float* __restrict__ b1_st,
    const float* __restrict__ Wself_tt, const float* __restrict__ Wneigh_tt, const float* __restrict__ b_tt,
    const float* __restrict__ Wneigh_hf, const float* __restrict__ b_hf,
    const float* __restrict__ W2_st, const float* __restrict__ b2_st,
    const float* __restrict__ W_out, const float* __restrict__ b_out,
    float* __restrict__ c_all, float* __restrict__ d_out) {
    __shared__ float hs[16][HID];
    __shared__ float hstile[16][NS];
    __shared__ float m[2][HID];
    __shared__ float ctt[2][HID];
    __shared__ float gsum[2];
    int tid = threadIdx.x;

    if (blockIdx.x < 304) {
        int t = blockIdx.x * 256 + tid;
        if (t < 28672) {
            int j = t & 7, cc = (t >> 3) & 15, kg = (t >> 7) & 3, q = t >> 9;
            int kc = q % 7, nc = q / 7;
            int n = nc * 16 + cc;
            int k = kc * 32 + ((j >> 2) << 4) + (kg << 2) + (j & 3);
            wsb[t] = (unsigned short)f2b(k < NF ? W1_ft[k * HID + n] : 0.f);
        } else {
            int u = t - 28672, l = u >> 14, v = u & 16383;
            int j = v & 7, cc = (v >> 3) & 15, kg = (v >> 7) & 3, kc = (v >> 9) & 3, nc = v >> 11;
            int n = nc * 16 + cc;
            int k = kc * 32 + ((j >> 2) << 4) + (kg << 2) + (j & 3);
            wsb[t] = (unsigned short)f2b(Wself_hf[(l * HID + k) * HID + n]);
        }
        return;
    }

    int bid = blockIdx.x - 304;
    int j = tid & 127, h = tid >> 7;
    int gblk = bid * 2;

    if (tid < 2) gsum[tid] = 0.f;
    if (tid < 128) hstile[tid >> 3][tid & 7] = h_st[bid * 128 + tid];
    __syncthreads();

    {
        float w1r[8];
#pragma unroll
        for (int k = 0; k < 8; k++) w1r[k] = W1_st[k * HID + j];
        float b1 = b1_st[j];
#pragma unroll
        for (int si = 0; si < 8; si++) {
            int s = 2 * si + h;
            float acc = b1;
#pragma unroll
            for (int k = 0; k < 8; k++) acc += hstile[s][k] * w1r[k];
            hs[s][j] = acc;
        }
    }
    __syncthreads();

    for (int l = 0; l < 3; l++) {
        {
            float s0 = 0.f;
#pragma unroll
            for (int s = 0; s < 8; s++) s0 += hs[h * 8 + s][j];
            m[h][j] = s0 * 0.125f;
        }
        __syncthreads();
        {
            float att = b_tt[l * HID + j], ahf = b_hf[l * HID + j];
            const float* wtt = Wneigh_tt + l * HID * HID + j;
            const float* whf = Wneigh_hf + l * HID * HID + j;
            const float* mg = m[h];
#pragma unroll 4
            for (int k = 0; k < HID; k++) {
                float mv = mg[k];
                att += mv * wtt[k * HID];
                ahf += mv * whf[k * HID];
            }
            ctt[h][j] = att;
            c_all[((gblk + h) * 3 + l) * HID + j] = ahf;
        }
        __syncthreads();
        float tmp[8];
#pragma unroll
        for (int si = 0; si < 8; si++) tmp[si] = ctt[(2 * si + h) >> 3][j];
        const float* wsp = Wself_tt + l * HID * HID + j;
        for (int k4 = 0; k4 < HID / 4; k4++) {
            float w0 = wsp[(4 * k4 + 0) * HID];
            float wa = wsp[(4 * k4 + 1) * HID];
            float wb = wsp[(4 * k4 + 2) * HID];
            float wc = wsp[(4 * k4 + 3) * HID];
#pragma unroll
            for (int si = 0; si < 8; si++) {
                float4a hv = *(const float4a*)&hs[2 * si + h][4 * k4];
                tmp[si] += hv.x * w0 + hv.y * wa + hv.z * wb + hv.w * wc;
            }
        }
        __syncthreads();
#pragma unroll
        for (int si = 0; si < 8; si++) hs[2 * si + h][j] = fmaxf(tmp[si], 0.f);
        __syncthreads();
    }

    int w = tid >> 6, lane = tid & 63;
    float w2a = W2_st[lane], w2b = W2_st[lane + 64];
    float p = 0.f;
#pragma unroll
    for (int r = 0; r < 4; r++) {
        int row = w * 4 + r;
        p += hs[row][lane] * w2a + hs[row][lane + 64] * w2b;
    }
#pragma unroll
    for (int off = 32; off; off >>= 1) p += __shfl_xor(p, off);
    if (lane == 0) atomicAdd(&gsum[w >> 1], p);
    __syncthreads();
    if (tid < 2) {
        float rs = gsum[tid] + 8.f * b2_st[0];
        d_out[gblk + tid] = rs * W_out[0] + b_out[0];
    }
}

// ---------------------------------------------------------------------------
// Feature path v10: 16-ROW units (1 row-tile/wave) sized to fit the 128-VGPR
// budget the backend pins us to (r4/r6/r7/r8/r9 all spilled with 2-tile
// working set ~160 regs; waves_per_eu attr ignored). Live set now ~90 regs:
// acc 32 + bf 16 + staging/addr ~40. 256 persistent blocks x 512 thr,
// full weight set (155,648 B) in LDS once, waves free-run over contiguous
// unit ranges (13440 units = 105/16 per wave). Layer-0 kc-outer.
// ---------------------------------------------------------------------------
__global__ __launch_bounds__(512) void feature_kernel(
    const float* __restrict__ h_ft, const float* __restrict__ b1_ft,
    const float* __restrict__ W2_ft, const float* __restrict__ b2_ft,
    const float* __restrict__ W_out,
    const unsigned short* __restrict__ wfrag, const float* __restrict__ c_all,
    float* __restrict__ d_out) {
    __shared__ __align__(16) unsigned short lw[77824];   // 155,648 B
    int tid = threadIdx.x;
    {
        const int4* gs = (const int4*)wfrag;
        int4* ls = (int4*)lw;
#pragma unroll
        for (int i = 0; i < 19; i++) ls[i * 512 + tid] = gs[i * 512 + tid];
    }
    __syncthreads();   // only barrier

    const int w = tid >> 6, lane = tid & 63;
    const int c = lane & 15, kg = lane >> 4;
    const int wid = blockIdx.x * 8 + w;
    const int u0 = (wid * 105) >> 4;          // 13440 units over 2048 waves
    const int u1 = ((wid + 1) * 105) >> 4;
    const short8v* w1l = (const short8v*)lw + lane;

    for (int u = u0; u < u1; ++u) {
        const int row = u * 16 + c;
        const int g = row / NF;
        const float* a0 = h_ft + (size_t)row * NF;

        float4v acc[8];
#pragma unroll
        for (int nc = 0; nc < 8; nc++)
#pragma unroll
            for (int r = 0; r < 4; r++) acc[nc][r] = 0.f;

        // ---- layer 0: kc-outer, load->convert->8 MFMA per kc ----
#pragma unroll
        for (int kc = 0; kc < 7; kc++) {
            const int k0 = kc * 32 + 4 * kg;
            float4u va = *(const float4u*)&a0[k0];
            float4u vb;
            if (kc < 6) {
                vb = *(const float4u*)&a0[k0 + 16];
            } else if (kg == 0) {
                float2u t0 = *(const float2u*)&a0[208];
                vb[0] = t0[0]; vb[1] = t0[1]; vb[2] = 0.f; vb[3] = 0.f;
            } else {
                vb[0] = vb[1] = vb[2] = vb[3] = 0.f;
            }
            short8v bx;
#pragma unroll
            for (int r = 0; r < 4; r++) {
                bx[r]     = f2b(va[r]);
                bx[4 + r] = f2b(vb[r]);
            }
            __builtin_amdgcn_s_setprio(1);
#pragma unroll
            for (int nc = 0; nc < 8; nc++) {
                short8v wv = w1l[(nc * 7 + kc) * 64];
                acc[nc] = MFMA16(wv, bx, acc[nc]);
            }
            __builtin_amdgcn_s_setprio(0);
        }

        // ---- transition: +b1, pack next-layer B-frags ----
        short8v bf[4];
#pragma unroll
        for (int k2 = 0; k2 < 4; k2++) {
            float4a bA = *(const float4a*)&b1_ft[k2 * 32 + 4 * kg];
            float4a bB = *(const float4a*)&b1_ft[k2 * 32 + 16 + 4 * kg];
#pragma unroll
            for (int r = 0; r < 4; r++) {
                bf[k2][r]     = f2b(acc[2 * k2][r]     + bA[r]);
                bf[k2][4 + r] = f2b(acc[2 * k2 + 1][r] + bB[r]);
            }
        }

        // ---- conv layers 0,1 ----
#pragma unroll
        for (int l = 0; l < 2; l++) {
            const short8v* wsl = (const short8v*)(lw + 28672 + l * 16384) + lane;
#pragma unroll
            for (int nc = 0; nc < 8; nc++)
#pragma unroll
                for (int r = 0; r < 4; r++) acc[nc][r] = 0.f;
            __builtin_amdgcn_s_setprio(1);
#pragma unroll
            for (int kc = 0; kc < 4; kc++)
#pragma unroll
                for (int nc = 0; nc < 8; nc++) {
                    short8v wv = wsl[(nc * 4 + kc) * 64];
                    acc[nc] = MFMA16(wv, bf[kc], acc[nc]);
                }
            __builtin_amdgcn_s_setprio(0);
            const float* cp = c_all + (g * 3 + l) * HID;
#pragma unroll
            for (int k2 = 0; k2 < 4; k2++) {
                float4a cA = *(const float4a*)&cp[k2 * 32 + 4 * kg];
                float4a cB = *(const float4a*)&cp[k2 * 32 + 16 + 4 * kg];
#pragma unroll
                for (int r = 0; r < 4; r++) {
                    bf[k2][r]     = f2b(fmaxf(acc[2 * k2][r]     + cA[r], 0.f));
                    bf[k2][4 + r] = f2b(fmaxf(acc[2 * k2 + 1][r] + cB[r], 0.f));
                }
            }
        }

        // ---- conv layer 2 + fused epilogue ----
        {
            const short8v* ws2 = (const short8v*)(lw + 61440) + lane;
#pragma unroll
            for (int nc = 0; nc < 8; nc++)
#pragma unroll
                for (int r = 0; r < 4; r++) acc[nc][r] = 0.f;
            __builtin_amdgcn_s_setprio(1);
#pragma unroll
            for (int kc = 0; kc < 4; kc++)
#pragma unroll
                for (int nc = 0; nc < 8; nc++) {
                    short8v wv = ws2[(nc * 4 + kc) * 64];
                    acc[nc] = MFMA16(wv, bf[kc], acc[nc]);
                }
            __builtin_amdgcn_s_setprio(0);
            const float* cp = c_all + (g * 3 + 2) * HID;
            float p0 = 0.f;
#pragma unroll
            for (int nc = 0; nc < 8; nc++) {
                float4a w2v = *(const float4a*)&W2_ft[nc * 16 + 4 * kg];
                float4a cv = *(const float4a*)&cp[nc * 16 + 4 * kg];
#pragma unroll
                for (int r = 0; r < 4; r++)
                    p0 += fmaxf(acc[nc][r] + cv[r], 0.f) * w2v[r];
            }
            p0 += __shfl_xor(p0, 16); p0 += __shfl_xor(p0, 32);
            if (kg == 0) {
                float wo1 = W_out[1], b2v = b2_ft[0];
                atomicAdd(&d_out[g], (p0 + b2v) * wo1);
            }
        }
    }
}

extern "C" void kernel_launch(void* const* d_in, const int* in_sizes, int n_in,
                              void* d_out, int out_size, void* d_ws, size_t ws_size,
                              hipStream_t stream) {
    const float* h_st     = (const float*)d_in[0];
    const float* h_ft     = (const float*)d_in[1];
    const float* Wself_tt = (const float*)d_in[2];
    const float* Wneigh_tt= (const float*)d_in[3];
    const float* b_tt     = (const float*)d_in[4];
    const float* Wself_hf = (const float*)d_in[5];
    const float* Wneigh_hf= (const float*)d_in[6];
    const float* b_hf     = (const float*)d_in[7];
    const float* W1_st    = (const float*)d_in[8];
    const float* b1_st    = (const float*)d_in[9];
    const float* W1_ft    = (const float*)d_in[10];
    const float* b1_ft    = (const float*)d_in[11];
    const float* W2_st    = (const float*)d_in[12];
    const float* b2_st    = (const float*)d_in[13];
    const float* W2_ft    = (const float*)d_in[14];
    const float* b2_ft    = (const float*)d_in[15];
    const float* W_out    = (const float*)d_in[16];
    const float* b_out    = (const float*)d_in[17];
    // dense edge lists d_in[18..21] never read

    unsigned short* wfrag = (unsigned short*)d_ws;
    float* c_all = (float*)((char*)d_ws + 155648);

    pre_kernel<<<dim3(816), dim3(256), 0, stream>>>(
        W1_ft, Wself_hf, wfrag,
        h_st, W1_st, b1_st, Wself_tt, Wneigh_tt, b_tt, Wneigh_hf, b_hf,
        W2_st, b2_st, W_out, b_out, c_all, (float*)d_out);
    feature_kernel<<<dim3(256), dim3(512), 0, stream>>>(
        h_ft, b1_ft, W2_ft, b2_ft, W_out, wfrag, c_all, (float*)d_out);
}

// Round 11
// 197.616 us; speedup vs baseline: 3.1302x; 3.1302x over previous
//
#include <hip/hip_runtime.h>
#include <hip/hip_bf16.h>

#define NS 8
#define NF 210
#define HID 128

typedef __attribute__((ext_vector_type(8))) short short8v;     // 8 bf16 MFMA A/B frag
typedef __attribute__((ext_vector_type(4))) float float4v;     // MFMA C/D frag
typedef float float4a __attribute__((ext_vector_type(4)));                 // 16B-aligned load
typedef float float4u __attribute__((ext_vector_type(4), aligned(4)));     // 4B-aligned global read
typedef float float2u __attribute__((ext_vector_type(2), aligned(8)));

__device__ __forceinline__ short f2b(float f) {
    __hip_bfloat16 h = __float2bfloat16(f);   // RNE
    return __builtin_bit_cast(short, h);
}

#define MFMA16(a, b, cacc) __builtin_amdgcn_mfma_f32_16x16x32_bf16(a, b, cacc, 0, 0, 0)

// ---------------------------------------------------------------------------
// pre_kernel: blocks [0,304) = weight repack; blocks [304,816) = station path.
// Blob (shorts): W1 @ 0 (28672), WsL @ 28672+l*16384. Frag elem j of lane
// (c,kg): n = 16nc+c, k = kc*32+16(j>=4)+4kg+(j&3). (unchanged, proven)
// ---------------------------------------------------------------------------
__global__ __launch_bounds__(256) void pre_kernel(
    const float* __restrict__ W1_ft, const float* __restrict__ Wself_hf,
    unsigned short* __restrict__ wsb,
    const float* __restrict__ h_st, const float* __restrict__ W1_st, const float* __restrict__ b1_st,
    const float* __restrict__ Wself_tt, const float* __restrict__ Wneigh_tt, const float* __restrict__ b_tt,
    const float* __restrict__ Wneigh_hf, const float* __restrict__ b_hf,
    const float* __restrict__ W2_st, const float* __restrict__ b2_st,
    const float* __restrict__ W_out, const float* __restrict__ b_out,
    float* __restrict__ c_all, float* __restrict__ d_out) {
    __shared__ float hs[16][HID];
    __shared__ float hstile[16][NS];
    __shared__ float m[2][HID];
    __shared__ float ctt[2][HID];
    __shared__ float gsum[2];
    int tid = threadIdx.x;

    if (blockIdx.x < 304) {
        int t = blockIdx.x * 256 + tid;
        if (t < 28672) {
            int j = t & 7, cc = (t >> 3) & 15, kg = (t >> 7) & 3, q = t >> 9;
            int kc = q % 7, nc = q / 7;
            int n = nc * 16 + cc;
            int k = kc * 32 + ((j >> 2) << 4) + (kg << 2) + (j & 3);
            wsb[t] = (unsigned short)f2b(k < NF ? W1_ft[k * HID + n] : 0.f);
        } else {
            int u = t - 28672, l = u >> 14, v = u & 16383;
            int j = v & 7, cc = (v >> 3) & 15, kg = (v >> 7) & 3, kc = (v >> 9) & 3, nc = v >> 11;
            int n = nc * 16 + cc;
            int k = kc * 32 + ((j >> 2) << 4) + (kg << 2) + (j & 3);
            wsb[t] = (unsigned short)f2b(Wself_hf[(l * HID + k) * HID + n]);
        }
        return;
    }

    int bid = blockIdx.x - 304;
    int j = tid & 127, h = tid >> 7;
    int gblk = bid * 2;

    if (tid < 2) gsum[tid] = 0.f;
    if (tid < 128) hstile[tid >> 3][tid & 7] = h_st[bid * 128 + tid];
    __syncthreads();

    {
        float w1r[8];
#pragma unroll
        for (int k = 0; k < 8; k++) w1r[k] = W1_st[k * HID + j];
        float b1 = b1_st[j];
#pragma unroll
        for (int si = 0; si < 8; si++) {
            int s = 2 * si + h;
            float acc = b1;
#pragma unroll
            for (int k = 0; k < 8; k++) acc += hstile[s][k] * w1r[k];
            hs[s][j] = acc;
        }
    }
    __syncthreads();

    for (int l = 0; l < 3; l++) {
        {
            float s0 = 0.f;
#pragma unroll
            for (int s = 0; s < 8; s++) s0 += hs[h * 8 + s][j];
            m[h][j] = s0 * 0.125f;
        }
        __syncthreads();
        {
            float att = b_tt[l * HID + j], ahf = b_hf[l * HID + j];
            const float* wtt = Wneigh_tt + l * HID * HID + j;
            const float* whf = Wneigh_hf + l * HID * HID + j;
            const float* mg = m[h];
#pragma unroll 4
            for (int k = 0; k < HID; k++) {
                float mv = mg[k];
                att += mv * wtt[k * HID];
                ahf += mv * whf[k * HID];
            }
            ctt[h][j] = att;
            c_all[((gblk + h) * 3 + l) * HID + j] = ahf;
        }
        __syncthreads();
        float tmp[8];
#pragma unroll
        for (int si = 0; si < 8; si++) tmp[si] = ctt[(2 * si + h) >> 3][j];
        const float* wsp = Wself_tt + l * HID * HID + j;
        for (int k4 = 0; k4 < HID / 4; k4++) {
            float w0 = wsp[(4 * k4 + 0) * HID];
            float wa = wsp[(4 * k4 + 1) * HID];
            float wb = wsp[(4 * k4 + 2) * HID];
            float wc = wsp[(4 * k4 + 3) * HID];
#pragma unroll
            for (int si = 0; si < 8; si++) {
                float4a hv = *(const float4a*)&hs[2 * si + h][4 * k4];
                tmp[si] += hv.x * w0 + hv.y * wa + hv.z * wb + hv.w * wc;
            }
        }
        __syncthreads();
#pragma unroll
        for (int si = 0; si < 8; si++) hs[2 * si + h][j] = fmaxf(tmp[si], 0.f);
        __syncthreads();
    }

    int w = tid >> 6, lane = tid & 63;
    float w2a = W2_st[lane], w2b = W2_st[lane + 64];
    float p = 0.f;
#pragma unroll
    for (int r = 0; r < 4; r++) {
        int row = w * 4 + r;
        p += hs[row][lane] * w2a + hs[row][lane + 64] * w2b;
    }
#pragma unroll
    for (int off = 32; off; off >>= 1) p += __shfl_xor(p, off);
    if (lane == 0) atomicAdd(&gsum[w >> 1], p);
    __syncthreads();
    if (tid < 2) {
        float rs = gsum[tid] + 8.f * b2_st[0];
        d_out[gblk + tid] = rs * W_out[0] + b_out[0];
    }
}

// ---------------------------------------------------------------------------
// Feature path v11: r3-replica codegen (122,880 B LDS, no setprio, 2-tile
// waves -> 92-VGPR-class compile) + slab loop for staging amortization.
// LDS (shorts): W1 @ 0 (resident), Ws0 @ 28672 (resident),
// R @ 45056 = swap region alternating Ws1 (conv l1) / Ws2 (conv l2).
// 256 blocks x 512 thr, block handles 3-4 contiguous 256-row slabs
// (840 total). Per slab: L0+conv0+conv1 -> bar -> stage Ws2->R -> bar ->
// conv2+epilogue -> [bar -> stage Ws1->R -> bar]. Direct global atomics.
// Every kernel with 155,648 B LDS (r4-r10) hit a 128-VGPR pin + 260-790 MB
// scratch; <=122,880 B compiles were clean (r2: 68, r3: 92 VGPR).
// ---------------------------------------------------------------------------
__device__ __forceinline__ short8v packA(const float* __restrict__ arp, int kc, int kg) {
    int k0 = kc * 32 + 4 * kg;
    float4u va = *(const float4u*)&arp[k0];
    float4u vb;
    if (kc < 6) {
        vb = *(const float4u*)&arp[k0 + 16];
    } else if (kg == 0) {
        float2u v2 = *(const float2u*)&arp[208];
        vb[0] = v2[0]; vb[1] = v2[1]; vb[2] = 0.f; vb[3] = 0.f;
    } else {
        vb[0] = 0.f; vb[1] = 0.f; vb[2] = 0.f; vb[3] = 0.f;
    }
    short8v r;
    r[0] = f2b(va[0]); r[1] = f2b(va[1]); r[2] = f2b(va[2]); r[3] = f2b(va[3]);
    r[4] = f2b(vb[0]); r[5] = f2b(vb[1]); r[6] = f2b(vb[2]); r[7] = f2b(vb[3]);
    return r;
}

__global__ __launch_bounds__(512) void feature_kernel(
    const float* __restrict__ h_ft, const float* __restrict__ b1_ft,
    const float* __restrict__ W2_ft, const float* __restrict__ b2_ft,
    const float* __restrict__ W_out,
    const unsigned short* __restrict__ wfrag, const float* __restrict__ c_all,
    float* __restrict__ d_out) {
    __shared__ __align__(16) unsigned short lw[61440];   // 122,880 B (r3 size)
    int tid = threadIdx.x;
    const int4* gs = (const int4*)wfrag;
    int4* ls = (int4*)lw;
    {   // stage W1 + Ws0 + Ws1 (Ws1 lands in R)
#pragma unroll
        for (int i = 0; i < 15; i++) ls[i * 512 + tid] = gs[i * 512 + tid];
    }
    __syncthreads();

    const int w = tid >> 6, lane = tid & 63;
    const int c = lane & 15, kg = lane >> 4;
    const int bid = blockIdx.x;
    const int s0 = (bid * 840) >> 8, s1 = ((bid + 1) * 840) >> 8;
    const short8v* w1l = (const short8v*)lw + lane;

    for (int S = s0; S < s1; ++S) {
        const int rb0 = S * 256 + w * 32;
        const int row0 = rb0 + c, row1 = rb0 + 16 + c;
        const int gA = row0 / NF, gB = row1 / NF;

        float4v acc0[8], acc1[8];
#pragma unroll
        for (int nc = 0; nc < 8; nc++)
#pragma unroll
            for (int r = 0; r < 4; r++) { acc0[nc][r] = 0.f; acc1[nc][r] = 0.f; }

        // ---- layer 0: X0^T = W1^T h_ft^T ----
        const float* arp0 = h_ft + (size_t)row0 * NF;
        const float* arp1 = h_ft + (size_t)row1 * NF;
#pragma unroll
        for (int kc = 0; kc < 7; kc++) {
            short8v bx0 = packA(arp0, kc, kg);
            short8v bx1 = packA(arp1, kc, kg);
#pragma unroll
            for (int nc = 0; nc < 8; nc++) {
                short8v wv = w1l[(nc * 7 + kc) * 64];
                acc0[nc] = MFMA16(wv, bx0, acc0[nc]);
                acc1[nc] = MFMA16(wv, bx1, acc1[nc]);
            }
        }

        // ---- transition: +b1, pack next-layer B-frags ----
        short8v bf0[4], bf1[4];
#pragma unroll
        for (int k2 = 0; k2 < 4; k2++) {
            float4a bA = *(const float4a*)&b1_ft[k2 * 32 + 4 * kg];
            float4a bB = *(const float4a*)&b1_ft[k2 * 32 + 16 + 4 * kg];
            short8v f0, f1;
#pragma unroll
            for (int r = 0; r < 4; r++) {
                f0[r]     = f2b(acc0[2 * k2][r] + bA[r]);
                f0[4 + r] = f2b(acc0[2 * k2 + 1][r] + bB[r]);
                f1[r]     = f2b(acc1[2 * k2][r] + bA[r]);
                f1[4 + r] = f2b(acc1[2 * k2 + 1][r] + bB[r]);
            }
            bf0[k2] = f0; bf1[k2] = f1;
        }

        // ---- conv layers 0 (Ws0 @28672) and 1 (Ws1 in R @45056) ----
#pragma unroll
        for (int l = 0; l < 2; l++) {
            const short8v* wsl = (const short8v*)(lw + 28672 + l * 16384) + lane;
#pragma unroll
            for (int nc = 0; nc < 8; nc++)
#pragma unroll
                for (int r = 0; r < 4; r++) { acc0[nc][r] = 0.f; acc1[nc][r] = 0.f; }
#pragma unroll
            for (int kc = 0; kc < 4; kc++)
#pragma unroll
                for (int nc = 0; nc < 8; nc++) {
                    short8v wv = wsl[(nc * 4 + kc) * 64];
                    acc0[nc] = MFMA16(wv, bf0[kc], acc0[nc]);
                    acc1[nc] = MFMA16(wv, bf1[kc], acc1[nc]);
                }
            const float* cp0 = c_all + (gA * 3 + l) * HID;
            const float* cp1 = c_all + (gB * 3 + l) * HID;
#pragma unroll
            for (int k2 = 0; k2 < 4; k2++) {
                float4a cA0 = *(const float4a*)&cp0[k2 * 32 + 4 * kg];
                float4a cB0 = *(const float4a*)&cp0[k2 * 32 + 16 + 4 * kg];
                float4a cA1 = *(const float4a*)&cp1[k2 * 32 + 4 * kg];
                float4a cB1 = *(const float4a*)&cp1[k2 * 32 + 16 + 4 * kg];
                short8v f0, f1;
#pragma unroll
                for (int r = 0; r < 4; r++) {
                    f0[r]     = f2b(fmaxf(acc0[2 * k2][r] + cA0[r], 0.f));
                    f0[4 + r] = f2b(fmaxf(acc0[2 * k2 + 1][r] + cB0[r], 0.f));
                    f1[r]     = f2b(fmaxf(acc1[2 * k2][r] + cA1[r], 0.f));
                    f1[4 + r] = f2b(fmaxf(acc1[2 * k2 + 1][r] + cB1[r], 0.f));
                }
                bf0[k2] = f0; bf1[k2] = f1;
            }
        }

        // ---- swap R: Ws1 -> Ws2 ----
        __syncthreads();
#pragma unroll
        for (int i = 0; i < 4; i++) ls[5632 + i * 512 + tid] = gs[7680 + i * 512 + tid];
        __syncthreads();

        // ---- conv layer 2 (Ws2 in R @45056) + fused epilogue ----
        {
            const short8v* ws2 = (const short8v*)(lw + 45056) + lane;
#pragma unroll
            for (int nc = 0; nc < 8; nc++)
#pragma unroll
                for (int r = 0; r < 4; r++) { acc0[nc][r] = 0.f; acc1[nc][r] = 0.f; }
#pragma unroll
            for (int kc = 0; kc < 4; kc++)
#pragma unroll
                for (int nc = 0; nc < 8; nc++) {
                    short8v wv = ws2[(nc * 4 + kc) * 64];
                    acc0[nc] = MFMA16(wv, bf0[kc], acc0[nc]);
                    acc1[nc] = MFMA16(wv, bf1[kc], acc1[nc]);
                }
            const float* cp0 = c_all + (gA * 3 + 2) * HID;
            const float* cp1 = c_all + (gB * 3 + 2) * HID;
            float p0 = 0.f, p1 = 0.f;
#pragma unroll
            for (int nc = 0; nc < 8; nc++) {
                float4a w2v = *(const float4a*)&W2_ft[nc * 16 + 4 * kg];
                float4a cv0 = *(const float4a*)&cp0[nc * 16 + 4 * kg];
                float4a cv1 = *(const float4a*)&cp1[nc * 16 + 4 * kg];
#pragma unroll
                for (int r = 0; r < 4; r++) {
                    p0 += fmaxf(acc0[nc][r] + cv0[r], 0.f) * w2v[r];
                    p1 += fmaxf(acc1[nc][r] + cv1[r], 0.f) * w2v[r];
                }
            }
            p0 += __shfl_xor(p0, 16); p0 += __shfl_xor(p0, 32);
            p1 += __shfl_xor(p1, 16); p1 += __shfl_xor(p1, 32);
            if (kg == 0) {
                float wo1 = W_out[1], b2v = b2_ft[0];
                atomicAdd(&d_out[gA], (p0 + b2v) * wo1);
                atomicAdd(&d_out[gB], (p1 + b2v) * wo1);
            }
        }

        // ---- restore R to Ws1 for next slab ----
        if (S + 1 < s1) {
            __syncthreads();
#pragma unroll
            for (int i = 0; i < 4; i++) ls[5632 + i * 512 + tid] = gs[5632 + i * 512 + tid];
            __syncthreads();
        }
    }
}

extern "C" void kernel_launch(void* const* d_in, const int* in_sizes, int n_in,
                              void* d_out, int out_size, void* d_ws, size_t ws_size,
                              hipStream_t stream) {
    const float* h_st     = (const float*)d_in[0];
    const float* h_ft     = (const float*)d_in[1];
    const float* Wself_tt = (const float*)d_in[2];
    const float* Wneigh_tt= (const float*)d_in[3];
    const float* b_tt     = (const float*)d_in[4];
    const float* Wself_hf = (const float*)d_in[5];
    const float* Wneigh_hf= (const float*)d_in[6];
    const float* b_hf     = (const float*)d_in[7];
    const float* W1_st    = (const float*)d_in[8];
    const float* b1_st    = (const float*)d_in[9];
    const float* W1_ft    = (const float*)d_in[10];
    const float* b1_ft    = (const float*)d_in[11];
    const float* W2_st    = (const float*)d_in[12];
    const float* b2_st    = (const float*)d_in[13];
    const float* W2_ft    = (const float*)d_in[14];
    const float* b2_ft    = (const float*)d_in[15];
    const float* W_out    = (const float*)d_in[16];
    const float* b_out    = (const float*)d_in[17];
    // dense edge lists d_in[18..21] never read

    unsigned short* wfrag = (unsigned short*)d_ws;
    float* c_all = (float*)((char*)d_ws + 155648);

    pre_kernel<<<dim3(816), dim3(256), 0, stream>>>(
        W1_ft, Wself_hf, wfrag,
        h_st, W1_st, b1_st, Wself_tt, Wneigh_tt, b_tt, Wneigh_hf, b_hf,
        W2_st, b2_st, W_out, b_out, c_all, (float*)d_out);
    feature_kernel<<<dim3(256), dim3(512), 0, stream>>>(
        h_ft, b1_ft, W2_ft, b2_ft, W_out, wfrag, c_all, (float*)d_out);
}